// Round 1
// baseline (14832.819 us; speedup 1.0000x reference)
//
#include <hip/hip_runtime.h>

#define D 10000
#define NROWS 16384
#define NC 100
#define BD 32
#define NCHUNK 313  // 313*32 = 10016 >= 10000 (tail zero-padded)

// ------------------------------------------------------------------
// K1: scores = encoded @ class_hvs^T  (fp32, vector ALU), argmax, mis mask
// block: 64 rows x 100 classes, 256 threads. lane = row-within-block,
// wave w owns classes [25w, 25w+25) in 25 register accumulators.
// A tile [64][BD] in LDS (pad 33), B tile [100][BD] in LDS, broadcast reads.
// Register-prefetch double buffering, one barrier per chunk.
// ------------------------------------------------------------------
__global__ __launch_bounds__(256) void k_scores(
    const float* __restrict__ enc, const float* __restrict__ hv,
    const int* __restrict__ tgt, float* __restrict__ out,
    int* __restrict__ predm, int* __restrict__ targm) {
  __shared__ float As[2][64 * 33];
  __shared__ float Bs[2][NC * BD];
  __shared__ float redv[256];
  __shared__ int redi[256];

  const int tid = threadIdx.x;
  const int lane = tid & 63;
  const int wave = tid >> 6;
  const int r0 = blockIdx.x * 64;
  const int c0 = wave * 25;

  float acc[25];
#pragma unroll
  for (int j = 0; j < 25; ++j) acc[j] = 0.f;

  const float4 zero4 = make_float4(0.f, 0.f, 0.f, 0.f);

  auto load_a = [&](int idx, int d0) -> float4 {
    int row = idx >> 3, d4 = idx & 7;
    int d = d0 + d4 * 4;
    if (d < D) return *(const float4*)&enc[(size_t)(r0 + row) * D + d];
    return zero4;
  };
  auto load_b = [&](int idx, int d0) -> float4 {
    int c = idx >> 3, d4 = idx & 7;
    int d = d0 + d4 * 4;
    if (d < D) return *(const float4*)&hv[(size_t)c * D + d];
    return zero4;
  };

  float4 a0, a1, b0, b1, b2, b3;

  auto store_tile = [&](int buf) {
    {
      int row = tid >> 3, d4 = tid & 7;
      float* p = &As[buf][row * 33 + d4 * 4];
      p[0] = a0.x; p[1] = a0.y; p[2] = a0.z; p[3] = a0.w;
    }
    {
      int idx = tid + 256;
      int row = idx >> 3, d4 = idx & 7;
      float* p = &As[buf][row * 33 + d4 * 4];
      p[0] = a1.x; p[1] = a1.y; p[2] = a1.z; p[3] = a1.w;
    }
    {
      int c = tid >> 3, d4 = tid & 7;
      *(float4*)&Bs[buf][c * BD + d4 * 4] = b0;
    }
    {
      int idx = tid + 256; int c = idx >> 3, d4 = idx & 7;
      *(float4*)&Bs[buf][c * BD + d4 * 4] = b1;
    }
    {
      int idx = tid + 512; int c = idx >> 3, d4 = idx & 7;
      *(float4*)&Bs[buf][c * BD + d4 * 4] = b2;
    }
    if (tid < 32) {
      int idx = tid + 768; int c = idx >> 3, d4 = idx & 7;
      *(float4*)&Bs[buf][c * BD + d4 * 4] = b3;
    }
  };

  // prefetch + stage chunk 0
  a0 = load_a(tid, 0); a1 = load_a(tid + 256, 0);
  b0 = load_b(tid, 0); b1 = load_b(tid + 256, 0); b2 = load_b(tid + 512, 0);
  b3 = (tid < 32) ? load_b(tid + 768, 0) : zero4;
  store_tile(0);

  for (int ch = 0; ch < NCHUNK; ++ch) {
    const int buf = ch & 1;
    const bool more = (ch + 1) < NCHUNK;
    if (more) {
      int d0 = (ch + 1) * BD;
      a0 = load_a(tid, d0); a1 = load_a(tid + 256, d0);
      b0 = load_b(tid, d0); b1 = load_b(tid + 256, d0); b2 = load_b(tid + 512, d0);
      if (tid < 32) b3 = load_b(tid + 768, d0);
    }
    __syncthreads();  // buf's data visible; previous compute done -> safe to overwrite other buf
#pragma unroll
    for (int dg = 0; dg < BD / 4; ++dg) {
      float av0 = As[buf][lane * 33 + dg * 4 + 0];
      float av1 = As[buf][lane * 33 + dg * 4 + 1];
      float av2 = As[buf][lane * 33 + dg * 4 + 2];
      float av3 = As[buf][lane * 33 + dg * 4 + 3];
#pragma unroll
      for (int j = 0; j < 25; ++j) {
        float4 b = *(const float4*)&Bs[buf][(c0 + j) * BD + dg * 4];
        acc[j] += av0 * b.x;
        acc[j] += av1 * b.y;
        acc[j] += av2 * b.z;
        acc[j] += av3 * b.w;
      }
    }
    if (more) store_tile(buf ^ 1);
  }

  // write scores
  const int row = r0 + lane;
  float* orow = out + (size_t)row * NC + c0;
#pragma unroll
  for (int j = 0; j < 25; ++j) orow[j] = acc[j];

  // per-thread argmax over its 25 classes (strict > keeps lowest index)
  float m = acc[0]; int mi = 0;
#pragma unroll
  for (int j = 1; j < 25; ++j) {
    if (acc[j] > m) { m = acc[j]; mi = j; }
  }
  redv[tid] = m;
  redi[tid] = c0 + mi;
  __syncthreads();
  if (tid < 64) {
    float bv = redv[tid]; int bi = redi[tid];
#pragma unroll
    for (int w = 1; w < 4; ++w) {
      float v = redv[w * 64 + tid];
      if (v > bv) { bv = v; bi = redi[w * 64 + tid]; }  // ascending class order => first-max kept
    }
    int t = tgt[r0 + tid];
    bool mis = (bi != t);
    predm[r0 + tid] = mis ? bi : -1;
    targm[r0 + tid] = mis ? t : -1;
  }
}

// ------------------------------------------------------------------
// K2: segment sums of misclassified rows, keyed by target (add) and pred (sub).
// block: 64 columns x 2048 rows (wave w does contiguous 512 rows).
// LDS accumulators [100][64] for both, then global atomic merge.
// ------------------------------------------------------------------
__global__ __launch_bounds__(256) void k_scatter(
    const float* __restrict__ enc, const int* __restrict__ predm,
    const int* __restrict__ targm, float* __restrict__ add,
    float* __restrict__ sub) {
  __shared__ float aacc[NC * 64];
  __shared__ float sacc[NC * 64];
  const int tid = threadIdx.x;
  for (int i = tid; i < NC * 64; i += 256) { aacc[i] = 0.f; sacc[i] = 0.f; }
  __syncthreads();

  const int lane = tid & 63;
  const int wave = tid >> 6;
  const int colbase = blockIdx.x * 64;
  const int col = colbase + lane;
  const bool cv = (col < D);
  const int rbase = blockIdx.y * 2048 + wave * 512;

  for (int i = 0; i < 512; i += 4) {
    int r = rbase + i;
    int t0 = targm[r + 0], t1 = targm[r + 1], t2 = targm[r + 2], t3 = targm[r + 3];
    int p0 = predm[r + 0], p1 = predm[r + 1], p2 = predm[r + 2], p3 = predm[r + 3];
    float v0 = cv ? enc[(size_t)(r + 0) * D + col] : 0.f;
    float v1 = cv ? enc[(size_t)(r + 1) * D + col] : 0.f;
    float v2 = cv ? enc[(size_t)(r + 2) * D + col] : 0.f;
    float v3 = cv ? enc[(size_t)(r + 3) * D + col] : 0.f;
    if (t0 >= 0) { unsafeAtomicAdd(&aacc[t0 * 64 + lane], v0); unsafeAtomicAdd(&sacc[p0 * 64 + lane], v0); }
    if (t1 >= 0) { unsafeAtomicAdd(&aacc[t1 * 64 + lane], v1); unsafeAtomicAdd(&sacc[p1 * 64 + lane], v1); }
    if (t2 >= 0) { unsafeAtomicAdd(&aacc[t2 * 64 + lane], v2); unsafeAtomicAdd(&sacc[p2 * 64 + lane], v2); }
    if (t3 >= 0) { unsafeAtomicAdd(&aacc[t3 * 64 + lane], v3); unsafeAtomicAdd(&sacc[p3 * 64 + lane], v3); }
  }
  __syncthreads();

  for (int i = tid; i < NC * 64; i += 256) {
    int c = i >> 6, cc = i & 63;
    int gcol = colbase + cc;
    if (gcol < D) {
      unsafeAtomicAdd(&add[(size_t)c * D + gcol], aacc[i]);
      unsafeAtomicAdd(&sub[(size_t)c * D + gcol], sacc[i]);
    }
  }
}

// ------------------------------------------------------------------
// K3: new_class_hvs = class_hvs + clip(add,-1,1) - clip(sub,-1,1)
// ------------------------------------------------------------------
__global__ __launch_bounds__(256) void k_update(
    const float* __restrict__ hv, const float* __restrict__ add,
    const float* __restrict__ sub, float* __restrict__ outhv) {
  int base = (blockIdx.x * 256 + threadIdx.x) * 4;
  if (base < NC * D) {
    float4 a = *(const float4*)&add[base];
    float4 s = *(const float4*)&sub[base];
    float4 h = *(const float4*)&hv[base];
    float4 o;
    o.x = h.x + fminf(fmaxf(a.x, -1.f), 1.f) - fminf(fmaxf(s.x, -1.f), 1.f);
    o.y = h.y + fminf(fmaxf(a.y, -1.f), 1.f) - fminf(fmaxf(s.y, -1.f), 1.f);
    o.z = h.z + fminf(fmaxf(a.z, -1.f), 1.f) - fminf(fmaxf(s.z, -1.f), 1.f);
    o.w = h.w + fminf(fmaxf(a.w, -1.f), 1.f) - fminf(fmaxf(s.w, -1.f), 1.f);
    *(float4*)&outhv[base] = o;
  }
}

extern "C" void kernel_launch(void* const* d_in, const int* in_sizes, int n_in,
                              void* d_out, int out_size, void* d_ws, size_t ws_size,
                              hipStream_t stream) {
  const float* enc = (const float*)d_in[0];
  const int* tgt = (const int*)d_in[1];
  const float* hv = (const float*)d_in[2];
  float* out = (float*)d_out;  // [16384*100 scores][100*10000 new_class_hvs]

  char* ws = (char*)d_ws;
  int* predm = (int*)ws;                       // 65536 B
  int* targm = (int*)(ws + 65536);             // 65536 B
  float* add = (float*)(ws + 131072);          // 4,000,000 B
  float* sub = (float*)(ws + 131072 + 4000000);// 4,000,000 B

  hipMemsetAsync(add, 0, 8000000, stream);

  k_scores<<<dim3(NROWS / 64), dim3(256), 0, stream>>>(enc, hv, tgt, out, predm, targm);
  k_scatter<<<dim3((D + 63) / 64, 8), dim3(256), 0, stream>>>(enc, predm, targm, add, sub);
  k_update<<<dim3((NC * D / 4 + 255) / 256), dim3(256), 0, stream>>>(
      hv, add, sub, out + (size_t)NROWS * NC);
}

// Round 2
// 4151.854 us; speedup vs baseline: 3.5726x; 3.5726x over previous
//
#include <hip/hip_runtime.h>

#define D 10000
#define NROWS 16384
#define NC 100
#define BD 32
#define NCHUNK 313  // 313*32 = 10016 >= 10000 (tail zero-padded)

// ------------------------------------------------------------------
// K1: scores = encoded @ class_hvs^T (fp32 vector ALU), argmax, mis mask.
// block: 256 thr = 4 waves, 64 rows. lane = row, wave w owns classes
// [25w, 25w+25). Single LDS buffer, 2-barrier K-loop with register
// prefetch of the next chunk (loads in flight during compute).
// Compute is j-outer: A row chunk hoisted to av[32] regs once, then per
// class 8 broadcast ds_read_b128 of B + 32 FMA. Bounded register set.
// ------------------------------------------------------------------
__global__ __launch_bounds__(256) void k_scores(
    const float* __restrict__ enc, const float* __restrict__ hv,
    const int* __restrict__ tgt, float* __restrict__ out,
    int* __restrict__ predm, int* __restrict__ targm) {
  __shared__ float As[64 * 33];   // pad 33: A reads (lane+k)%32 conflict-free
  __shared__ float Bs[NC * BD];   // B reads wave-uniform (broadcast)
  __shared__ float redv[256];
  __shared__ int redi[256];

  const int tid = threadIdx.x;
  const int lane = tid & 63;
  const int wave = tid >> 6;
  const int r0 = blockIdx.x * 64;
  const int c0 = wave * 25;

  float acc[25];
#pragma unroll
  for (int j = 0; j < 25; ++j) acc[j] = 0.f;

  const int arow = tid >> 3;       // 0..31
  const int d4 = (tid & 7) * 4;    // 0..28 step 4
  const int bc = tid >> 3;         // 0..31

  const float4 zero4 = make_float4(0.f, 0.f, 0.f, 0.f);
  float4 pa0, pa1, pb0, pb1, pb2, pb3;

  // preload chunk 0 into registers (all of chunk 0 is in-bounds)
  pa0 = *(const float4*)&enc[(size_t)(r0 + arow) * D + d4];
  pa1 = *(const float4*)&enc[(size_t)(r0 + arow + 32) * D + d4];
  pb0 = *(const float4*)&hv[(size_t)bc * D + d4];
  pb1 = *(const float4*)&hv[(size_t)(bc + 32) * D + d4];
  pb2 = *(const float4*)&hv[(size_t)(bc + 64) * D + d4];
  pb3 = (tid < 32) ? *(const float4*)&hv[(size_t)(96 + bc) * D + d4] : zero4;

  for (int ch = 0; ch < NCHUNK; ++ch) {
    __syncthreads();  // prior compute's LDS reads done; prefetch drained
    // stage registers -> LDS
    As[arow * 33 + d4 + 0] = pa0.x;
    As[arow * 33 + d4 + 1] = pa0.y;
    As[arow * 33 + d4 + 2] = pa0.z;
    As[arow * 33 + d4 + 3] = pa0.w;
    As[(arow + 32) * 33 + d4 + 0] = pa1.x;
    As[(arow + 32) * 33 + d4 + 1] = pa1.y;
    As[(arow + 32) * 33 + d4 + 2] = pa1.z;
    As[(arow + 32) * 33 + d4 + 3] = pa1.w;
    *(float4*)&Bs[bc * BD + d4] = pb0;
    *(float4*)&Bs[(bc + 32) * BD + d4] = pb1;
    *(float4*)&Bs[(bc + 64) * BD + d4] = pb2;
    if (tid < 32) *(float4*)&Bs[(96 + bc) * BD + d4] = pb3;
    __syncthreads();  // stores visible

    // prefetch next chunk (in flight during compute below)
    if (ch + 1 < NCHUNK) {
      const int d = (ch + 1) * BD + d4;
      const bool v = d < D;  // D%4==0 so d<D implies d+3<D
      pa0 = v ? *(const float4*)&enc[(size_t)(r0 + arow) * D + d] : zero4;
      pa1 = v ? *(const float4*)&enc[(size_t)(r0 + arow + 32) * D + d] : zero4;
      pb0 = v ? *(const float4*)&hv[(size_t)bc * D + d] : zero4;
      pb1 = v ? *(const float4*)&hv[(size_t)(bc + 32) * D + d] : zero4;
      pb2 = v ? *(const float4*)&hv[(size_t)(bc + 64) * D + d] : zero4;
      pb3 = (v && tid < 32) ? *(const float4*)&hv[(size_t)(96 + bc) * D + d] : zero4;
    }

    // compute: hoist this lane's A chunk into registers once
    float av[32];
#pragma unroll
    for (int k = 0; k < 32; ++k) av[k] = As[lane * 33 + k];
#pragma unroll
    for (int j = 0; j < 25; ++j) {
      float s = acc[j];
#pragma unroll
      for (int dg = 0; dg < 8; ++dg) {
        float4 b = *(const float4*)&Bs[(c0 + j) * BD + dg * 4];
        s += av[dg * 4 + 0] * b.x;
        s += av[dg * 4 + 1] * b.y;
        s += av[dg * 4 + 2] * b.z;
        s += av[dg * 4 + 3] * b.w;
      }
      acc[j] = s;
    }
  }

  // write scores
  const int row = r0 + lane;
  float* orow = out + (size_t)row * NC + c0;
#pragma unroll
  for (int j = 0; j < 25; ++j) orow[j] = acc[j];

  // per-thread argmax over its 25 classes (strict > keeps lowest index)
  float m = acc[0];
  int mi = 0;
#pragma unroll
  for (int j = 1; j < 25; ++j) {
    if (acc[j] > m) { m = acc[j]; mi = j; }
  }
  redv[tid] = m;
  redi[tid] = c0 + mi;
  __syncthreads();
  if (tid < 64) {
    float bv = redv[tid];
    int bi = redi[tid];
#pragma unroll
    for (int w = 1; w < 4; ++w) {
      float v = redv[w * 64 + tid];
      if (v > bv) { bv = v; bi = redi[w * 64 + tid]; }  // ascending class order => first-max kept
    }
    int t = tgt[r0 + tid];
    bool mis = (bi != t);
    predm[r0 + tid] = mis ? bi : -1;
    targm[r0 + tid] = mis ? t : -1;
  }
}

// ------------------------------------------------------------------
// K2: segment sums of misclassified rows, keyed by target (add) and pred (sub).
// block: 64 columns x 2048 rows (wave w does contiguous 512 rows).
// LDS accumulators [100][64] for both, then global atomic merge.
// ------------------------------------------------------------------
__global__ __launch_bounds__(256) void k_scatter(
    const float* __restrict__ enc, const int* __restrict__ predm,
    const int* __restrict__ targm, float* __restrict__ add,
    float* __restrict__ sub) {
  __shared__ float aacc[NC * 64];
  __shared__ float sacc[NC * 64];
  const int tid = threadIdx.x;
  for (int i = tid; i < NC * 64; i += 256) { aacc[i] = 0.f; sacc[i] = 0.f; }
  __syncthreads();

  const int lane = tid & 63;
  const int wave = tid >> 6;
  const int colbase = blockIdx.x * 64;
  const int col = colbase + lane;
  const bool cv = (col < D);
  const int rbase = blockIdx.y * 2048 + wave * 512;

  for (int i = 0; i < 512; i += 4) {
    int r = rbase + i;
    int t0 = targm[r + 0], t1 = targm[r + 1], t2 = targm[r + 2], t3 = targm[r + 3];
    int p0 = predm[r + 0], p1 = predm[r + 1], p2 = predm[r + 2], p3 = predm[r + 3];
    float v0 = cv ? enc[(size_t)(r + 0) * D + col] : 0.f;
    float v1 = cv ? enc[(size_t)(r + 1) * D + col] : 0.f;
    float v2 = cv ? enc[(size_t)(r + 2) * D + col] : 0.f;
    float v3 = cv ? enc[(size_t)(r + 3) * D + col] : 0.f;
    if (t0 >= 0) { unsafeAtomicAdd(&aacc[t0 * 64 + lane], v0); unsafeAtomicAdd(&sacc[p0 * 64 + lane], v0); }
    if (t1 >= 0) { unsafeAtomicAdd(&aacc[t1 * 64 + lane], v1); unsafeAtomicAdd(&sacc[p1 * 64 + lane], v1); }
    if (t2 >= 0) { unsafeAtomicAdd(&aacc[t2 * 64 + lane], v2); unsafeAtomicAdd(&sacc[p2 * 64 + lane], v2); }
    if (t3 >= 0) { unsafeAtomicAdd(&aacc[t3 * 64 + lane], v3); unsafeAtomicAdd(&sacc[p3 * 64 + lane], v3); }
  }
  __syncthreads();

  for (int i = tid; i < NC * 64; i += 256) {
    int c = i >> 6, cc = i & 63;
    int gcol = colbase + cc;
    if (gcol < D) {
      unsafeAtomicAdd(&add[(size_t)c * D + gcol], aacc[i]);
      unsafeAtomicAdd(&sub[(size_t)c * D + gcol], sacc[i]);
    }
  }
}

// ------------------------------------------------------------------
// K3: new_class_hvs = class_hvs + clip(add,-1,1) - clip(sub,-1,1)
// ------------------------------------------------------------------
__global__ __launch_bounds__(256) void k_update(
    const float* __restrict__ hv, const float* __restrict__ add,
    const float* __restrict__ sub, float* __restrict__ outhv) {
  int base = (blockIdx.x * 256 + threadIdx.x) * 4;
  if (base < NC * D) {
    float4 a = *(const float4*)&add[base];
    float4 s = *(const float4*)&sub[base];
    float4 h = *(const float4*)&hv[base];
    float4 o;
    o.x = h.x + fminf(fmaxf(a.x, -1.f), 1.f) - fminf(fmaxf(s.x, -1.f), 1.f);
    o.y = h.y + fminf(fmaxf(a.y, -1.f), 1.f) - fminf(fmaxf(s.y, -1.f), 1.f);
    o.z = h.z + fminf(fmaxf(a.z, -1.f), 1.f) - fminf(fmaxf(s.z, -1.f), 1.f);
    o.w = h.w + fminf(fmaxf(a.w, -1.f), 1.f) - fminf(fmaxf(s.w, -1.f), 1.f);
    *(float4*)&outhv[base] = o;
  }
}

extern "C" void kernel_launch(void* const* d_in, const int* in_sizes, int n_in,
                              void* d_out, int out_size, void* d_ws, size_t ws_size,
                              hipStream_t stream) {
  const float* enc = (const float*)d_in[0];
  const int* tgt = (const int*)d_in[1];
  const float* hv = (const float*)d_in[2];
  float* out = (float*)d_out;  // [16384*100 scores][100*10000 new_class_hvs]

  char* ws = (char*)d_ws;
  int* predm = (int*)ws;                        // 65536 B
  int* targm = (int*)(ws + 65536);              // 65536 B
  float* add = (float*)(ws + 131072);           // 4,000,000 B
  float* sub = (float*)(ws + 131072 + 4000000); // 4,000,000 B

  hipMemsetAsync(add, 0, 8000000, stream);

  k_scores<<<dim3(NROWS / 64), dim3(256), 0, stream>>>(enc, hv, tgt, out, predm, targm);
  k_scatter<<<dim3((D + 63) / 64, 8), dim3(256), 0, stream>>>(enc, predm, targm, add, sub);
  k_update<<<dim3((NC * D / 4 + 255) / 256), dim3(256), 0, stream>>>(
      hv, add, sub, out + (size_t)NROWS * NC);
}